// Round 1
// baseline (274.222 us; speedup 1.0000x reference)
//
#include <hip/hip_runtime.h>

#define BATCH 4096
#define SEQT  512
#define HID   32
#define CHUNK 64

#if __has_builtin(__builtin_amdgcn_exp2f)
#define FAST_EXP2(x) __builtin_amdgcn_exp2f(x)
#else
#define FAST_EXP2(x) exp2f(x)
#endif
#if __has_builtin(__builtin_amdgcn_rcpf)
#define FAST_RCP(x) __builtin_amdgcn_rcpf(x)
#else
#define FAST_RCP(x) (1.0f / (x))
#endif

// One wave (64 lanes) per block; each wave owns 2 sequences.
// lane = g*32 + j : g = sequence-within-wave, j = hidden index.
// W_hh row j lives in 32 VGPRs per lane; h lives in LDS, read back each
// step as group-uniform ds_read_b128 (broadcast, conflict-free).
__global__ __launch_bounds__(64, 2) void rnn_kernel(
    const float* __restrict__ x,      // [B, T]   (INPUT==1)
    const float* __restrict__ h0,     // [B, H]
    const float* __restrict__ W_ih,   // [H]      (INPUT==1)
    const float* __restrict__ b_ih,   // [H]
    const float* __restrict__ W_hh,   // [H, H]   row-major, out[j] = sum_k h[k]*W_hh[j][k]
    const float* __restrict__ b_hh,   // [H]
    const float* __restrict__ W_out,  // [H]
    const float* __restrict__ b_out,  // [1]
    float* __restrict__ out)          // [B*T] outs, then [B*H] hT
{
    const int lane = threadIdx.x;     // 0..63
    const int g    = lane >> 5;       // 0 or 1
    const int j    = lane & 31;       // hidden index
    const int b0   = blockIdx.x * 2;  // first sequence of this wave
    const int b    = b0 + g;

    __shared__ float hbuf[2][HID];
    __shared__ float xbuf[2][CHUNK];
    __shared__ float obuf[2][CHUNK];

    // ---- load weights into registers ----
    float Wrow[HID];
    {
        const float4* wr = reinterpret_cast<const float4*>(W_hh + j * HID);
        #pragma unroll
        for (int k = 0; k < 8; ++k) {
            float4 v = wr[k];
            Wrow[4 * k + 0] = v.x;
            Wrow[4 * k + 1] = v.y;
            Wrow[4 * k + 2] = v.z;
            Wrow[4 * k + 3] = v.w;
        }
    }
    const float wih  = W_ih[j];
    const float bias = b_ih[j] + b_hh[j];   // fold both biases
    const float wout = W_out[j];
    const float bout = b_out[0];

    float h = h0[b * HID + j];
    hbuf[g][j] = h;
    __syncthreads();

    const float* xrow0 = x   + (size_t)b0 * SEQT;  // sequence b0 row
    float*       orow0 = out + (size_t)b0 * SEQT;

    for (int tc = 0; tc < SEQT; tc += CHUNK) {
        // ---- stage x for both sequences (coalesced) ----
        xbuf[0][lane] = xrow0[tc + lane];
        xbuf[1][lane] = xrow0[SEQT + tc + lane];
        __syncthreads();

        #pragma unroll 4
        for (int t2 = 0; t2 < CHUNK; ++t2) {
            const float xv = xbuf[g][t2];
            float acc = fmaf(xv, wih, bias);

            // h-matvec: 8 group-uniform b128 reads + 32 FMAs
            const float4* h4 = reinterpret_cast<const float4*>(hbuf[g]);
            #pragma unroll
            for (int k = 0; k < 8; ++k) {
                float4 hv = h4[k];
                acc = fmaf(hv.x, Wrow[4 * k + 0], acc);
                acc = fmaf(hv.y, Wrow[4 * k + 1], acc);
                acc = fmaf(hv.z, Wrow[4 * k + 2], acc);
                acc = fmaf(hv.w, Wrow[4 * k + 3], acc);
            }

            // tanh(acc) = 1 - 2/(exp2(acc*2*log2e) + 1); saturates correctly
            const float e    = FAST_EXP2(acc * 2.8853900817779268f);
            const float hnew = fmaf(-2.0f, FAST_RCP(e + 1.0f), 1.0f);

            // output dot: butterfly-reduce h*wout over the 32-lane group
            float p = hnew * wout;
            #pragma unroll
            for (int off = 16; off; off >>= 1)
                p += __shfl_xor(p, off, 32);
            if (j == 0) obuf[g][t2] = p + bout;

            h = hnew;
            __syncthreads();          // reads of hbuf done (1-wave block: ~free)
            hbuf[g][j] = hnew;
            __syncthreads();          // write visible before next step's reads
        }

        // ---- flush outputs coalesced ----
        orow0[tc + lane]        = obuf[0][lane];
        orow0[SEQT + tc + lane] = obuf[1][lane];
    }

    // final hidden state: [1, B, H] at offset B*T
    out[(size_t)BATCH * SEQT + (size_t)b * HID + j] = h;
}

extern "C" void kernel_launch(void* const* d_in, const int* in_sizes, int n_in,
                              void* d_out, int out_size, void* d_ws, size_t ws_size,
                              hipStream_t stream) {
    const float* x     = (const float*)d_in[0];
    const float* h0    = (const float*)d_in[1];
    const float* W_ih  = (const float*)d_in[2];
    const float* b_ih  = (const float*)d_in[3];
    const float* W_hh  = (const float*)d_in[4];
    const float* b_hh  = (const float*)d_in[5];
    const float* W_out = (const float*)d_in[6];
    const float* b_out = (const float*)d_in[7];
    float* outp = (float*)d_out;

    dim3 grid(BATCH / 2);   // 2048 one-wave blocks
    dim3 block(64);
    hipLaunchKernelGGL(rnn_kernel, grid, block, 0, stream,
                       x, h0, W_ih, b_ih, W_hh, b_hh, W_out, b_out, outp);
}

// Round 2
// 195.984 us; speedup vs baseline: 1.3992x; 1.3992x over previous
//
#include <hip/hip_runtime.h>

#define BATCH 4096
#define SEQT  512
#define HID   32
#define CHUNK 64

#if __has_builtin(__builtin_amdgcn_exp2f)
#define FAST_EXP2(x) __builtin_amdgcn_exp2f(x)
#else
#define FAST_EXP2(x) exp2f(x)
#endif
#if __has_builtin(__builtin_amdgcn_rcpf)
#define FAST_RCP(x) __builtin_amdgcn_rcpf(x)
#else
#define FAST_RCP(x) (1.0f / (x))
#endif

// One wave (64 lanes) per SEQUENCE; 2 sequences (2 waves) per 128-thread block.
// lane = 2*j + s : j = hidden index (0..31), s = k-half (0..1).
// Lane (j,s) accumulates sum_{k in [16s,16s+16)} W_hh[j][k]*h[k]; halves are
// combined with one __shfl_xor(.,1) (stays inside a 32-lane group -> cheap).
// h history for the current 64-step chunk lives in a per-wave LDS slice;
// NO __syncthreads in the steady state -- intra-wave DS ops are in-order
// (wave-synchronous LDS), wave_barrier() pins compiler ordering.
// Outputs are computed OFF the recurrence path in a chunk-end pass with
// rotation-swizzled ((t+k)&31) bank-conflict-free reads.
__global__ __launch_bounds__(128, 4) void rnn_kernel(
    const float* __restrict__ x,      // [B, T]
    const float* __restrict__ h0,     // [B, H]
    const float* __restrict__ W_ih,   // [H]
    const float* __restrict__ b_ih,   // [H]
    const float* __restrict__ W_hh,   // [H, H] row-major
    const float* __restrict__ b_hh,   // [H]
    const float* __restrict__ W_out,  // [H]
    const float* __restrict__ b_out,  // [1]
    float* __restrict__ out)          // [B*T] outs, then [B*H] hT
{
    const int tid  = threadIdx.x;
    const int wv   = tid >> 6;        // wave in block: 0 or 1
    const int lane = tid & 63;
    const int j    = lane >> 1;       // hidden index
    const int s    = lane & 1;        // k-half
    const int b    = blockIdx.x * 2 + wv;

    __shared__ float hist_s[2][CHUNK * HID];  // 8 KB per sequence
    __shared__ float xbuf_s[2][CHUNK];
    __shared__ float wbuf[HID];

    float* hist = hist_s[wv];
    float* xbuf = xbuf_s[wv];

    if (tid < HID) wbuf[tid] = W_out[tid];

    // per-lane W_hh half-row (16 floats) in registers
    float Wr[16];
    {
        const float4* wr = reinterpret_cast<const float4*>(W_hh + j * HID + 16 * s);
        #pragma unroll
        for (int k = 0; k < 4; ++k) {
            float4 v = wr[k];
            Wr[4 * k + 0] = v.x; Wr[4 * k + 1] = v.y;
            Wr[4 * k + 2] = v.z; Wr[4 * k + 3] = v.w;
        }
    }
    // bias/input-proj contributed by half 0 only (halves sum via shfl_xor)
    const float wih  = s ? 0.0f : W_ih[j];
    const float bias = s ? 0.0f : (b_ih[j] + b_hh[j]);
    const float bout = b_out[0];

    // seed h_{-1} into the wrap slot; both lanes of a pair write the same
    // value to the same address (well-defined: identical data)
    hist[(CHUNK - 1) * HID + j] = h0[b * HID + j];

    __syncthreads();  // wbuf + seed visible (one-time)

    // W_out pre-rotated into registers for the chunk-end output pass
    float wo[HID];
    #pragma unroll
    for (int k = 0; k < HID; ++k) wo[k] = wbuf[(lane + k) & (HID - 1)];

    const float* xg = x + (size_t)b * SEQT;
    float*       og = out + (size_t)b * SEQT;

    float hcur = 0.0f;

    for (int tc = 0; tc < SEQT; tc += CHUNK) {
        // stage x chunk (coalesced)
        xbuf[lane] = xg[tc + lane];
        __builtin_amdgcn_wave_barrier();

        #pragma unroll 16
        for (int t2 = 0; t2 < CHUNK; ++t2) {
            const int tprev = (t2 + CHUNK - 1) & (CHUNK - 1);
            const float4* h4 =
                reinterpret_cast<const float4*>(hist + tprev * HID + 16 * s);
            float4 va = h4[0], vb = h4[1], vc = h4[2], vd = h4[3];
            const float xv = xbuf[t2];

            // 16 FMAs in 4 independent chains (depth ~7 max)
            float a0 = fmaf(xv, wih, bias);
            a0 = fmaf(va.x, Wr[0], a0);  a0 = fmaf(va.y, Wr[1], a0);
            float a1 = va.z * Wr[2];     a1 = fmaf(va.w, Wr[3], a1);
            a0 = fmaf(vb.x, Wr[4], a0);  a1 = fmaf(vb.y, Wr[5], a1);
            float a2 = vb.z * Wr[6];     a2 = fmaf(vb.w, Wr[7], a2);
            float a3 = vc.x * Wr[8];     a3 = fmaf(vc.y, Wr[9], a3);
            a0 = fmaf(vc.z, Wr[10], a0); a1 = fmaf(vc.w, Wr[11], a1);
            a2 = fmaf(vd.x, Wr[12], a2); a3 = fmaf(vd.y, Wr[13], a3);
            a0 = fmaf(vd.z, Wr[14], a0); a1 = fmaf(vd.w, Wr[15], a1);
            float part = (a0 + a1) + (a2 + a3);

            // combine k-halves (pair 2j <-> 2j+1)
            part += __shfl_xor(part, 1, 64);

            // tanh(p) = 1 - 2/(exp2(2p*log2e)+1); saturates correctly
            const float e    = FAST_EXP2(part * 2.8853900817779268f);
            const float hnew = fmaf(-2.0f, FAST_RCP(e + 1.0f), 1.0f);

            // both pair-lanes write the same value to the same address
            hist[t2 * HID + j] = hnew;
            __builtin_amdgcn_wave_barrier();
            hcur = hnew;
        }

        // ---- chunk-end output pass: lane t computes out[tc+t] ----
        // rotated index keeps all 64 lanes bank-conflict-free (2-way max)
        float o = bout;
        const float* hrow = hist + lane * HID;
        #pragma unroll
        for (int k = 0; k < HID; ++k) {
            const int kk = (lane + k) & (HID - 1);
            o = fmaf(hrow[kk], wo[k], o);
        }
        og[tc + lane] = o;  // coalesced
        __builtin_amdgcn_wave_barrier();
    }

    // final hidden state [1,B,H]; pair-lanes store same value
    out[(size_t)BATCH * SEQT + (size_t)b * HID + j] = hcur;
}

extern "C" void kernel_launch(void* const* d_in, const int* in_sizes, int n_in,
                              void* d_out, int out_size, void* d_ws, size_t ws_size,
                              hipStream_t stream) {
    const float* x     = (const float*)d_in[0];
    const float* h0    = (const float*)d_in[1];
    const float* W_ih  = (const float*)d_in[2];
    const float* b_ih  = (const float*)d_in[3];
    const float* W_hh  = (const float*)d_in[4];
    const float* b_hh  = (const float*)d_in[5];
    const float* W_out = (const float*)d_in[6];
    const float* b_out = (const float*)d_in[7];
    float* outp = (float*)d_out;

    dim3 grid(BATCH / 2);   // 2048 blocks x 2 waves = 4096 waves (1 per sequence)
    dim3 block(128);
    hipLaunchKernelGGL(rnn_kernel, grid, block, 0, stream,
                       x, h0, W_ih, b_ih, W_hh, b_hh, W_out, b_out, outp);
}

// Round 3
// 157.856 us; speedup vs baseline: 1.7372x; 1.2415x over previous
//
#include <hip/hip_runtime.h>

#define BATCH 4096
#define SEQT  512
#define HID   32
#define CH    32     // timestep chunk == hist rows
#define ROWP  40     // padded hist row stride in f16 units (80 B: 16B-aligned, kills 16-bank aliasing)
#define WPB   4      // waves per block

typedef _Float16 f16;
typedef _Float16 h2 __attribute__((ext_vector_type(2)));

#if __has_builtin(__builtin_amdgcn_fdot2)
#define FDOT2(a, b, c) __builtin_amdgcn_fdot2((a), (b), (c), false)
#else
#define FDOT2(a, b, c) fmaf((float)(a)[1], (float)(b)[1], fmaf((float)(a)[0], (float)(b)[0], (c)))
#endif

#if __has_builtin(__builtin_amdgcn_exp2f)
#define FAST_EXP2(x) __builtin_amdgcn_exp2f(x)
#else
#define FAST_EXP2(x) exp2f(x)
#endif
#if __has_builtin(__builtin_amdgcn_rcpf)
#define FAST_RCP(x) __builtin_amdgcn_rcpf(x)
#else
#define FAST_RCP(x) (1.0f / (x))
#endif

#define BC(x) __builtin_bit_cast(h2, (x))

// One wave handles TWO sequences: lane = g*32 + j (g = seq-in-wave, j = hidden).
// h state is f16 in a per-wave private LDS slice; each lane reads the FULL
// previous-h row (64 B) with 4 broadcast ds_read_b128 and computes the whole
// k-sum with 16 v_dot2_f32_f16 (f32 accumulate) -- no shuffles, no k-split.
// All DS ops are per-wave and in-order => NO barriers anywhere (wave_barrier
// only pins compiler ordering). Output dot is off the recurrence path, done
// chunk-end via fdot2 from the same f16 history (rows padded to 80 B so the
// 32 row-strided lanes land 4-way max on banks).
__global__ __launch_bounds__(64 * WPB, 2) void rnn_kernel(
    const float* __restrict__ x,      // [B, T]
    const float* __restrict__ h0,     // [B, H]
    const float* __restrict__ W_ih,   // [H]
    const float* __restrict__ b_ih,   // [H]
    const float* __restrict__ W_hh,   // [H, H] row-major
    const float* __restrict__ b_hh,   // [H]
    const float* __restrict__ W_out,  // [H]
    const float* __restrict__ b_out,  // [1]
    float* __restrict__ out)          // [B*T] outs, then [B*H] hT
{
    const int tid  = threadIdx.x;
    const int wv   = tid >> 6;
    const int lane = tid & 63;
    const int g    = lane >> 5;
    const int j    = lane & 31;       // hidden index; doubles as t-index in staging passes
    const int bseq = blockIdx.x * (2 * WPB) + 2 * wv + g;

    __shared__ f16   hist_s[WPB][2][CH][ROWP];
    __shared__ float xbuf_s[WPB][2][CH];

    f16*   hist = &hist_s[wv][g][0][0];
    float* xbuf = &xbuf_s[wv][g][0];

    // ---- W_hh row j packed to f16 pairs (16 dwords in VGPRs) ----
    h2 Wr[16];
    {
        const float4* wrow = reinterpret_cast<const float4*>(W_hh + j * HID);
        #pragma unroll
        for (int m = 0; m < 8; ++m) {
            float4 v = wrow[m];
            Wr[2 * m + 0] = h2{(f16)v.x, (f16)v.y};
            Wr[2 * m + 1] = h2{(f16)v.z, (f16)v.w};
        }
    }
    // ---- W_out packed to f16 pairs ----
    h2 Wo[16];
    {
        const float4* wrow = reinterpret_cast<const float4*>(W_out);
        #pragma unroll
        for (int m = 0; m < 8; ++m) {
            float4 v = wrow[m];
            Wo[2 * m + 0] = h2{(f16)v.x, (f16)v.y};
            Wo[2 * m + 1] = h2{(f16)v.z, (f16)v.w};
        }
    }
    const float wih  = W_ih[j];
    const float bias = b_ih[j] + b_hh[j];
    const float bout = b_out[0];

    // seed h_{-1} into the wrap row (row CH-1)
    hist[(CH - 1) * ROWP + j] = (f16)h0[bseq * HID + j];
    __builtin_amdgcn_wave_barrier();

    const float* xg = x + (size_t)bseq * SEQT;
    float*       og = out + (size_t)bseq * SEQT;

    float hT = 0.0f;

    for (int tc = 0; tc < SEQT; tc += CH) {
        // stage x chunk (lane j acts as t-index; coalesced 2x128B per wave)
        xbuf[j] = xg[tc + j];
        __builtin_amdgcn_wave_barrier();

        float xc = xbuf[0];

        #pragma unroll
        for (int t2 = 0; t2 < CH; ++t2) {
            const f16* rp = hist + ((t2 + CH - 1) & (CH - 1)) * ROWP;
            const float4 q0 = reinterpret_cast<const float4*>(rp)[0];
            const float4 q1 = reinterpret_cast<const float4*>(rp)[1];
            const float4 q2 = reinterpret_cast<const float4*>(rp)[2];
            const float4 q3 = reinterpret_cast<const float4*>(rp)[3];
            const float xn = xbuf[(t2 + 1) & (CH - 1)];  // next step's x, off-chain

            // 16 fdot2 in 4 independent chains (depth 4)
            float a0 = fmaf(xc, wih, bias);
            a0 = FDOT2(BC(q0.x), Wr[0],  a0);
            float a1 = FDOT2(BC(q0.y), Wr[1],  0.0f);
            float a2 = FDOT2(BC(q0.z), Wr[2],  0.0f);
            float a3 = FDOT2(BC(q0.w), Wr[3],  0.0f);
            a0 = FDOT2(BC(q1.x), Wr[4],  a0);
            a1 = FDOT2(BC(q1.y), Wr[5],  a1);
            a2 = FDOT2(BC(q1.z), Wr[6],  a2);
            a3 = FDOT2(BC(q1.w), Wr[7],  a3);
            a0 = FDOT2(BC(q2.x), Wr[8],  a0);
            a1 = FDOT2(BC(q2.y), Wr[9],  a1);
            a2 = FDOT2(BC(q2.z), Wr[10], a2);
            a3 = FDOT2(BC(q2.w), Wr[11], a3);
            a0 = FDOT2(BC(q3.x), Wr[12], a0);
            a1 = FDOT2(BC(q3.y), Wr[13], a1);
            a2 = FDOT2(BC(q3.z), Wr[14], a2);
            a3 = FDOT2(BC(q3.w), Wr[15], a3);
            const float part = (a0 + a1) + (a2 + a3);

            // tanh(p) = 1 - 2/(exp2(2p*log2e)+1); saturates correctly at +-inf
            const float e  = FAST_EXP2(part * 2.8853900817779268f);
            const float hn = fmaf(-2.0f, FAST_RCP(e + 1.0f), 1.0f);

            hist[t2 * ROWP + j] = (f16)hn;
            __builtin_amdgcn_wave_barrier();

            xc = xn;
            hT = hn;
        }

        // ---- chunk-end output pass: lane (g, t=j) computes out[tc+j] ----
        {
            const f16* rp = hist + j * ROWP;
            const float4 q0 = reinterpret_cast<const float4*>(rp)[0];
            const float4 q1 = reinterpret_cast<const float4*>(rp)[1];
            const float4 q2 = reinterpret_cast<const float4*>(rp)[2];
            const float4 q3 = reinterpret_cast<const float4*>(rp)[3];
            float o0 = FDOT2(BC(q0.x), Wo[0],  bout);
            float o1 = FDOT2(BC(q0.y), Wo[1],  0.0f);
            float o2 = FDOT2(BC(q0.z), Wo[2],  0.0f);
            float o3 = FDOT2(BC(q0.w), Wo[3],  0.0f);
            o0 = FDOT2(BC(q1.x), Wo[4],  o0);
            o1 = FDOT2(BC(q1.y), Wo[5],  o1);
            o2 = FDOT2(BC(q1.z), Wo[6],  o2);
            o3 = FDOT2(BC(q1.w), Wo[7],  o3);
            o0 = FDOT2(BC(q2.x), Wo[8],  o0);
            o1 = FDOT2(BC(q2.y), Wo[9],  o1);
            o2 = FDOT2(BC(q2.z), Wo[10], o2);
            o3 = FDOT2(BC(q2.w), Wo[11], o3);
            o0 = FDOT2(BC(q3.x), Wo[12], o0);
            o1 = FDOT2(BC(q3.y), Wo[13], o1);
            o2 = FDOT2(BC(q3.z), Wo[14], o2);
            o3 = FDOT2(BC(q3.w), Wo[15], o3);
            og[tc + j] = (o0 + o1) + (o2 + o3);
        }
        __builtin_amdgcn_wave_barrier();
    }

    // final hidden state [1, B, H]
    out[(size_t)BATCH * SEQT + (size_t)bseq * HID + j] = hT;
}

extern "C" void kernel_launch(void* const* d_in, const int* in_sizes, int n_in,
                              void* d_out, int out_size, void* d_ws, size_t ws_size,
                              hipStream_t stream) {
    const float* x     = (const float*)d_in[0];
    const float* h0    = (const float*)d_in[1];
    const float* W_ih  = (const float*)d_in[2];
    const float* b_ih  = (const float*)d_in[3];
    const float* W_hh  = (const float*)d_in[4];
    const float* b_hh  = (const float*)d_in[5];
    const float* W_out = (const float*)d_in[6];
    const float* b_out = (const float*)d_in[7];
    float* outp = (float*)d_out;

    dim3 grid(BATCH / (2 * WPB));   // 512 blocks x 4 waves x 2 seqs/wave
    dim3 block(64 * WPB);
    hipLaunchKernelGGL(rnn_kernel, grid, block, 0, stream,
                       x, h0, W_ih, b_ih, W_hh, b_hh, W_out, b_out, outp);
}